// Round 2
// baseline (469.237 us; speedup 1.0000x reference)
//
#include <hip/hip_runtime.h>
#include <hip/hip_fp16.h>

// CapsuleLayer dynamic routing — round 2: multi-kernel split for occupancy.
// Key insight: logits need no storage: logits_r = bias + hat.v1 (+ hat.v2),
// and hat is recomputed each round anyway. So each routing round is one
// wide kernel over (i-chunk, b) = 2304 blocks; squash kernels in between.
// Wave w of each 640-thread block owns output capsule j=w: softmax row data
// is shared via one LDS barrier; s-reduction is an in-wave butterfly + 16
// global atomics per wave (9-way contention per (b,j,d)).

#define IC 1152
#define IE 8
#define NC 10
#define DV 16
#define NB 256
#define NW (IC * NC * IE * DV)  // 1,474,560
#define CHUNK 128
#define NCHUNK (IC / CHUNK)     // 9
#define TPB 640                 // 10 waves; wave w handles j = w
#define SOUT (NC * DV)          // 160

__global__ void w2h_kernel(const float* __restrict__ W, __half* __restrict__ Wh) {
    const int k = blockIdx.x * blockDim.x + threadIdx.x;  // n4 = NW/4 = 368640
    if (k < NW / 4) {
        float4 w = ((const float4*)W)[k];
        __half2* o = (__half2*)Wh + 2 * (size_t)k;
        o[0] = __floats2half2_rn(w.x, w.y);
        o[1] = __floats2half2_rn(w.z, w.w);
    }
}

__global__ void zero_kernel(float4* __restrict__ p) {
    p[blockIdx.x * blockDim.x + threadIdx.x] = make_float4(0.f, 0.f, 0.f, 0.f);
}

template <int R, bool USE_H>
__global__ __launch_bounds__(TPB) void round_kernel(
    const float* __restrict__ X,     // [B, IC, IE]
    const void* __restrict__ Wv,     // [IC, NC, IE, DV] fp16 (or fp32)
    const float* __restrict__ bias,  // [IC*NC]
    const float* __restrict__ v1ws,  // [B*160] (R>=1)
    const float* __restrict__ v2ws,  // [B*160] (R==2)
    float* __restrict__ s_ws)        // [B*160] accumulated via atomics
{
    __shared__ float lg[CHUNK * 11];  // logits tile, padded stride 11 (bank-safe)
    __shared__ float vA[SOUT], vB[SOUT];

    const int chunk = blockIdx.x, b = blockIdx.y;
    const int tid = threadIdx.x;
    const int j = tid >> 6;   // wave index = output capsule
    const int g = tid & 63;   // lane = row-in-group

    if (R >= 1) {
        if (tid < SOUT) vA[tid] = v1ws[(size_t)b * SOUT + tid];
        if (R == 2 && tid < SOUT) vB[tid] = v2ws[(size_t)b * SOUT + tid];
        __syncthreads();
    }

    const float* xb = X + (size_t)b * IC * IE;
    float hat[2][DV];

#pragma unroll
    for (int p = 0; p < 2; ++p) {
        const int row = g + 64 * p;
        const int i = chunk * CHUNK + row;

        const float4* xr = (const float4*)(xb + (size_t)i * IE);
        float4 x0 = xr[0], x1 = xr[1];
        float xe[IE] = {x0.x, x0.y, x0.z, x0.w, x1.x, x1.y, x1.z, x1.w};

#pragma unroll
        for (int d = 0; d < DV; ++d) hat[p][d] = 0.f;

        if (USE_H) {
            const float4* wp =
                (const float4*)((const __half*)Wv + (size_t)(i * NC + j) * IE * DV);
#pragma unroll
            for (int e = 0; e < IE; ++e) {
                float4 wa = wp[2 * e];
                float4 wb = wp[2 * e + 1];
                const __half2* ha = (const __half2*)&wa;
                const __half2* hb = (const __half2*)&wb;
                float ie = xe[e];
#pragma unroll
                for (int q = 0; q < 4; ++q) {
                    float2 fa = __half22float2(ha[q]);
                    float2 fb = __half22float2(hb[q]);
                    hat[p][2 * q]         = fmaf(ie, fa.x, hat[p][2 * q]);
                    hat[p][2 * q + 1]     = fmaf(ie, fa.y, hat[p][2 * q + 1]);
                    hat[p][8 + 2 * q]     = fmaf(ie, fb.x, hat[p][8 + 2 * q]);
                    hat[p][8 + 2 * q + 1] = fmaf(ie, fb.y, hat[p][8 + 2 * q + 1]);
                }
            }
        } else {
            const float4* wp =
                (const float4*)((const float*)Wv + (size_t)(i * NC + j) * IE * DV);
#pragma unroll
            for (int e = 0; e < IE; ++e) {
                float ie = xe[e];
#pragma unroll
                for (int q = 0; q < 4; ++q) {
                    float4 w = wp[4 * e + q];
                    hat[p][4 * q]     = fmaf(ie, w.x, hat[p][4 * q]);
                    hat[p][4 * q + 1] = fmaf(ie, w.y, hat[p][4 * q + 1]);
                    hat[p][4 * q + 2] = fmaf(ie, w.z, hat[p][4 * q + 2]);
                    hat[p][4 * q + 3] = fmaf(ie, w.w, hat[p][4 * q + 3]);
                }
            }
        }

        // logits_r = bias (+ hat.v1 (+ hat.v2)) — never stored across rounds
        float lt = bias[i * NC + j];
        if (R >= 1) {
            float a = 0.f;
#pragma unroll
            for (int d = 0; d < DV; ++d) a = fmaf(hat[p][d], vA[j * DV + d], a);
            lt += a;
        }
        if (R == 2) {
            float a = 0.f;
#pragma unroll
            for (int d = 0; d < DV; ++d) a = fmaf(hat[p][d], vB[j * DV + d], a);
            lt += a;
        }
        lg[row * 11 + j] = lt;
    }

    __syncthreads();  // the ONE barrier ordering logits writes vs softmax reads

    float s_acc[DV];
#pragma unroll
    for (int d = 0; d < DV; ++d) s_acc[d] = 0.f;

#pragma unroll
    for (int p = 0; p < 2; ++p) {
        const int row = g + 64 * p;
        const float* lr = &lg[row * 11];
        float mx = lr[0];
#pragma unroll
        for (int jj = 1; jj < NC; ++jj) mx = fmaxf(mx, lr[jj]);
        float Z = 0.f;
#pragma unroll
        for (int jj = 0; jj < NC; ++jj) Z += __expf(lr[jj] - mx);
        float c = __expf(lr[j] - mx) / Z;
#pragma unroll
        for (int d = 0; d < DV; ++d) s_acc[d] = fmaf(c, hat[p][d], s_acc[d]);
    }

    // in-wave butterfly: all 64 lanes share j, reduce over the 128 rows
#pragma unroll
    for (int off = 32; off >= 1; off >>= 1) {
#pragma unroll
        for (int d = 0; d < DV; ++d) s_acc[d] += __shfl_xor(s_acc[d], off);
    }
    if (g == 0) {
        float* sp = s_ws + (size_t)b * SOUT + j * DV;
#pragma unroll
        for (int d = 0; d < DV; ++d) atomicAdd(sp + d, s_acc[d]);
    }
}

__global__ __launch_bounds__(192) void squash_kernel(const float* __restrict__ s_ws,
                                                     float* __restrict__ vout) {
    const int b = blockIdx.x, t = threadIdx.x;
    if (t < SOUT) {
        float sv = s_ws[(size_t)b * SOUT + t];
        float s2 = sv * sv;
#pragma unroll
        for (int mk = 8; mk >= 1; mk >>= 1) s2 += __shfl_xor(s2, mk, 16);
        float scale = sqrtf(s2) / (1.f + s2);
        vout[(size_t)b * SOUT + t] = scale * sv;
    }
}

extern "C" void kernel_launch(void* const* d_in, const int* in_sizes, int n_in,
                              void* d_out, int out_size, void* d_ws, size_t ws_size,
                              hipStream_t stream) {
    const float* X = (const float*)d_in[0];     // [256,1152,8]
    const float* W = (const float*)d_in[1];     // [1152,10,8,16]
    const float* bias = (const float*)d_in[2];  // [1,1152,10]
    float* out = (float*)d_out;

    float* base = (float*)d_ws;
    const size_t SB = (size_t)NB * SOUT;  // 40960 floats per s/v buffer

    const size_t need_h = (size_t)(NW / 2 + 5 * SB) * sizeof(float);  // ~3.77 MB
    const bool use_h = (ws_size >= need_h);

    float* s0;
    if (use_h) s0 = base + NW / 2;  // Wh occupies NW halves = NW/2 floats
    else       s0 = base;
    float* s1 = s0 + SB;
    float* s2 = s1 + SB;
    float* v1 = s2 + SB;
    float* v2 = v1 + SB;

    // zero s0..s2 (contiguous 3*SB floats = 30720 float4)
    zero_kernel<<<dim3(120), dim3(256), 0, stream>>>((float4*)s0);

    dim3 rg(NCHUNK, NB);  // (9, 256)

    if (use_h) {
        __half* Wh = (__half*)d_ws;
        w2h_kernel<<<dim3(1440), dim3(256), 0, stream>>>(W, Wh);
        round_kernel<0, true><<<rg, TPB, 0, stream>>>(X, Wh, bias, nullptr, nullptr, s0);
        squash_kernel<<<NB, 192, 0, stream>>>(s0, v1);
        round_kernel<1, true><<<rg, TPB, 0, stream>>>(X, Wh, bias, v1, nullptr, s1);
        squash_kernel<<<NB, 192, 0, stream>>>(s1, v2);
        round_kernel<2, true><<<rg, TPB, 0, stream>>>(X, Wh, bias, v1, v2, s2);
        squash_kernel<<<NB, 192, 0, stream>>>(s2, out);
    } else {
        round_kernel<0, false><<<rg, TPB, 0, stream>>>(X, W, bias, nullptr, nullptr, s0);
        squash_kernel<<<NB, 192, 0, stream>>>(s0, v1);
        round_kernel<1, false><<<rg, TPB, 0, stream>>>(X, W, bias, v1, nullptr, s1);
        squash_kernel<<<NB, 192, 0, stream>>>(s1, v2);
        round_kernel<2, false><<<rg, TPB, 0, stream>>>(X, W, bias, v1, v2, s2);
        squash_kernel<<<NB, 192, 0, stream>>>(s2, out);
    }
}

// Round 3
// 211.854 us; speedup vs baseline: 2.2149x; 2.2149x over previous
//
#include <hip/hip_runtime.h>
#include <hip/hip_fp16.h>

// CapsuleLayer dynamic routing — round 3: coalesced W layout + register W reuse.
// Prep kernel gathers W (fp32 [i][j][e][d]) into fp16 Wc[G][j][d][g][e] where
// G=i>>6, g=i&63: lane-consecutive 16B chunks -> every W load is coalesced.
// Round kernel: block=(G, b-group of 4). Thread (lane g, wave j) holds its
// 256B W fragment in 16 int4 REGISTERS and reuses it for 4 batch elements
// (4x less L2 traffic). hat via v_dot2_f32_f16; s-reduction via a
// vector-splitting butterfly (64 instr instead of 192).

#define IC 1152
#define IE 8
#define NC 10
#define DV 16
#define NB 256
#define NW (IC * NC * IE * DV)  // 1,474,560
#define NG (IC / 64)            // 18 row-groups of 64
#define BT 4                    // batch elements per block
#define NBG (NB / BT)           // 64
#define TPB 640                 // wave w <-> output capsule j=w
#define SOUT (NC * DV)          // 160
#define SB (NB * SOUT)          // 40,960 floats per s/v buffer

typedef _Float16 h2 __attribute__((ext_vector_type(2)));
union WChunk { int4 v; h2 p[4]; _Float16 h[8]; };

#if defined(__has_builtin) && __has_builtin(__builtin_amdgcn_fdot2)
__device__ inline float fdot2(h2 a, h2 b, float c) {
    return __builtin_amdgcn_fdot2(a, b, c, false);
}
#else
__device__ inline float fdot2(h2 a, h2 b, float c) {
    return fmaf((float)a.x, (float)b.x, fmaf((float)a.y, (float)b.y, c));
}
#endif

// Gather-transpose W into the coalesced fp16 layout. One thread per 16B chunk.
__global__ void wprep_kernel(const float* __restrict__ W, int4* __restrict__ Wc) {
    const int t = blockIdx.x * blockDim.x + threadIdx.x;  // 184320 chunks
    if (t >= NW / 8) return;
    const int g = t & 63;
    const int r = t >> 6;
    const int d = r & 15;
    const int r2 = r >> 4;
    const int j = r2 % NC;
    const int G = r2 / NC;
    const int i = G * 64 + g;
    const float* src = W + ((size_t)(i * NC + j) * IE) * DV + d;  // e-stride DV
    WChunk c;
#pragma unroll
    for (int e = 0; e < IE; ++e) c.h[e] = (_Float16)src[(size_t)e * DV];
    Wc[t] = c.v;
}

__global__ void zero_kernel(float4* __restrict__ p) {
    p[blockIdx.x * blockDim.x + threadIdx.x] = make_float4(0.f, 0.f, 0.f, 0.f);
}

template <int R>
__global__ __launch_bounds__(TPB) void round_kernel(
    const float* __restrict__ X,     // [B, IC, IE] fp32
    const int4* __restrict__ Wc,     // coalesced fp16 layout
    const float* __restrict__ bias,  // [IC*NC] fp32
    const float* __restrict__ v1ws,  // [B*160] (R>=1)
    const float* __restrict__ v2ws,  // [B*160] (R==2)
    float* __restrict__ s_ws)        // [B*160] accumulated via atomics
{
    __shared__ float lg[64 * 11];  // logits tile for the 64 rows, stride 11

    const int G = blockIdx.x;   // row group 0..17
    const int bg = blockIdx.y;  // batch group 0..63
    const int tid = threadIdx.x;
    const int j = tid >> 6;  // wave = output capsule
    const int g = tid & 63;  // lane = row within group
    const int i = G * 64 + g;

    // W fragment: 16 chunks (one per d), lane-consecutive => coalesced.
    WChunk w[DV];
    {
        const int4* wp = Wc + ((size_t)(G * NC + j) * DV) * 64 + g;
#pragma unroll
        for (int d = 0; d < DV; ++d) w[d].v = wp[d * 64];
    }
    const float lt_bias = bias[i * NC + j];

    for (int bi = 0; bi < BT; ++bi) {
        const int b = bg * BT + bi;

        // X row i for batch b -> 4 half2 e-pairs
        const float4* xr = (const float4*)(X + ((size_t)b * IC + i) * IE);
        float4 x0 = xr[0], x1 = xr[1];
        h2 x2[4];
        x2[0] = h2{(_Float16)x0.x, (_Float16)x0.y};
        x2[1] = h2{(_Float16)x0.z, (_Float16)x0.w};
        x2[2] = h2{(_Float16)x1.x, (_Float16)x1.y};
        x2[3] = h2{(_Float16)x1.z, (_Float16)x1.w};

        // hat[i,j,d] = sum_e x[e] * W[i,j,e,d]
        float hat[DV];
#pragma unroll
        for (int d = 0; d < DV; ++d) {
            float a = 0.f;
#pragma unroll
            for (int q = 0; q < 4; ++q) a = fdot2(x2[q], w[d].p[q], a);
            hat[d] = a;
        }

        // logits = bias (+ hat.v1 (+ hat.v2)); v* are wave-uniform broadcasts
        float lt = lt_bias;
        if (R >= 1) {
            const float4* vp = (const float4*)(v1ws + (size_t)b * SOUT + j * DV);
            float4 v0 = vp[0], v1 = vp[1], v2 = vp[2], v3 = vp[3];
            const float* vf = (const float*)&v0;  // contiguous f0..f3 in regs
            float a = 0.f;
            {
                const float vv[DV] = {v0.x, v0.y, v0.z, v0.w, v1.x, v1.y, v1.z, v1.w,
                                      v2.x, v2.y, v2.z, v2.w, v3.x, v3.y, v3.z, v3.w};
#pragma unroll
                for (int d = 0; d < DV; ++d) a = fmaf(hat[d], vv[d], a);
            }
            (void)vf;
            lt += a;
        }
        if (R == 2) {
            const float4* vp = (const float4*)(v2ws + (size_t)b * SOUT + j * DV);
            float4 v0 = vp[0], v1 = vp[1], v2 = vp[2], v3 = vp[3];
            const float vv[DV] = {v0.x, v0.y, v0.z, v0.w, v1.x, v1.y, v1.z, v1.w,
                                  v2.x, v2.y, v2.z, v2.w, v3.x, v3.y, v3.z, v3.w};
            float a = 0.f;
#pragma unroll
            for (int d = 0; d < DV; ++d) a = fmaf(hat[d], vv[d], a);
            lt += a;
        }

        lg[g * 11 + j] = lt;
        __syncthreads();

        // row softmax over j (redundant across waves, 10 LDS reads)
        const float* lr = &lg[g * 11];
        float mx = lr[0];
#pragma unroll
        for (int jj = 1; jj < NC; ++jj) mx = fmaxf(mx, lr[jj]);
        float Z = 0.f;
#pragma unroll
        for (int jj = 0; jj < NC; ++jj) Z += __expf(lr[jj] - mx);
        float c = __expf(lr[j] - mx) / Z;
        __syncthreads();  // lg consumed; safe to overwrite next bi

        float s_acc[DV];
#pragma unroll
        for (int d = 0; d < DV; ++d) s_acc[d] = c * hat[d];

        // vector-splitting butterfly: 64 lanes x 16 values -> lane holds d=(g>>2)&15
        float r8[8];
#pragma unroll
        for (int d = 0; d < 8; ++d) {
            bool hi = (g & 32);
            float mine = hi ? s_acc[d + 8] : s_acc[d];
            float send = hi ? s_acc[d] : s_acc[d + 8];
            r8[d] = mine + __shfl_xor(send, 32);
        }
        float r4[4];
#pragma unroll
        for (int d = 0; d < 4; ++d) {
            bool hi = (g & 16);
            float mine = hi ? r8[d + 4] : r8[d];
            float send = hi ? r8[d] : r8[d + 4];
            r4[d] = mine + __shfl_xor(send, 16);
        }
        float r2v[2];
#pragma unroll
        for (int d = 0; d < 2; ++d) {
            bool hi = (g & 8);
            float mine = hi ? r4[d + 2] : r4[d];
            float send = hi ? r4[d] : r4[d + 2];
            r2v[d] = mine + __shfl_xor(send, 8);
        }
        float r1;
        {
            bool hi = (g & 4);
            float mine = hi ? r2v[1] : r2v[0];
            float send = hi ? r2v[0] : r2v[1];
            r1 = mine + __shfl_xor(send, 4);
        }
        r1 += __shfl_xor(r1, 2);
        r1 += __shfl_xor(r1, 1);

        if ((g & 3) == 0) {
            const int dd = (g >> 2) & 15;
            atomicAdd(&s_ws[(size_t)b * SOUT + j * DV + dd], r1);
        }
    }
}

__global__ __launch_bounds__(192) void squash_kernel(const float* __restrict__ s_ws,
                                                     float* __restrict__ vout) {
    const int b = blockIdx.x, t = threadIdx.x;
    if (t < SOUT) {
        float sv = s_ws[(size_t)b * SOUT + t];
        float s2 = sv * sv;
#pragma unroll
        for (int mk = 8; mk >= 1; mk >>= 1) s2 += __shfl_xor(s2, mk, 16);
        float scale = sqrtf(s2) / (1.f + s2);
        vout[(size_t)b * SOUT + t] = scale * sv;
    }
}

extern "C" void kernel_launch(void* const* d_in, const int* in_sizes, int n_in,
                              void* d_out, int out_size, void* d_ws, size_t ws_size,
                              hipStream_t stream) {
    const float* X = (const float*)d_in[0];     // [256,1152,8]
    const float* W = (const float*)d_in[1];     // [1152,10,8,16]
    const float* bias = (const float*)d_in[2];  // [1,1152,10]
    float* out = (float*)d_out;

    // workspace layout (floats): Wc (NW/2) | s0 | s1 | s2 | v1 | v2
    float* base = (float*)d_ws;
    int4* Wc = (int4*)d_ws;
    float* s0 = base + NW / 2;
    float* s1 = s0 + SB;
    float* s2 = s1 + SB;
    float* v1 = s2 + SB;
    float* v2 = v1 + SB;

    wprep_kernel<<<dim3(720), dim3(256), 0, stream>>>(W, Wc);
    zero_kernel<<<dim3(120), dim3(256), 0, stream>>>((float4*)s0);  // s0,s1,s2

    dim3 rg(NG, NBG);  // (18, 64)
    round_kernel<0><<<rg, TPB, 0, stream>>>(X, Wc, bias, nullptr, nullptr, s0);
    squash_kernel<<<NB, 192, 0, stream>>>(s0, v1);
    round_kernel<1><<<rg, TPB, 0, stream>>>(X, Wc, bias, v1, nullptr, s1);
    squash_kernel<<<NB, 192, 0, stream>>>(s1, v2);
    round_kernel<2><<<rg, TPB, 0, stream>>>(X, Wc, bias, v1, v2, s2);
    squash_kernel<<<NB, 192, 0, stream>>>(s2, out);
}

// Round 4
// 188.652 us; speedup vs baseline: 2.4873x; 1.1230x over previous
//
#include <hip/hip_runtime.h>
#include <hip/hip_fp16.h>

// CapsuleLayer dynamic routing — round 4: d-split lane mapping for occupancy.
// Lane = (d-half h, row r): W fragment is 8 int4 = 32 VGPRs (was 64), so two
// 10-wave blocks fit per CU. Z-table softmax (wave 0 computes 1/Z per row,
// others do 1 exp + 1 mul, no max-subtract — logits bounded ~±5). Round 0's
// softmax is b-independent -> hoisted (no barriers in its bi loop). Round 2
// uses vsum = v1+v2 (computed in squash) so it costs the same as round 1.

#define IC 1152
#define IE 8
#define NC 10
#define DV 16
#define NB 256
#define NW (IC * NC * IE * DV)  // 1,474,560
#define NGP (IC / 32)           // 36 row-groups of 32
#define BT 8                    // batch elements per block
#define NBG (NB / BT)           // 32
#define TPB 640                 // wave w <-> output capsule j=w
#define SOUT (NC * DV)          // 160
#define SB (NB * SOUT)          // 40,960 floats per s/v buffer

typedef _Float16 h2 __attribute__((ext_vector_type(2)));
union WChunk { int4 v; h2 p[4]; _Float16 h[8]; };

#if defined(__has_builtin) && __has_builtin(__builtin_amdgcn_fdot2)
__device__ inline float fdot2(h2 a, h2 b, float c) {
    return __builtin_amdgcn_fdot2(a, b, c, false);
}
#else
__device__ inline float fdot2(h2 a, h2 b, float c) {
    return fmaf((float)a.x, (float)b.x, fmaf((float)a.y, (float)b.y, c));
}
#endif

// W fp32 [i][j][e][d] -> fp16 chunks Wc[((Gp*10+j)*8+k)*64 + lane], where
// lane = h*32+r, i = Gp*32+r, d = h*8+k; chunk holds e=0..7 halves of W[i,j,:,d].
__global__ void wprep_kernel(const float* __restrict__ W, int4* __restrict__ Wc) {
    const int t = blockIdx.x * blockDim.x + threadIdx.x;
    if (t >= NW / 8) return;
    const int lane = t & 63;
    const int h = lane >> 5, r = lane & 31;
    const int k = (t >> 6) & 7;
    const int r2 = t >> 9;  // Gp*10 + j
    const int j = r2 % NC, Gp = r2 / NC;
    const int i = Gp * 32 + r;
    const int d = h * 8 + k;
    const float* src = W + ((size_t)(i * NC + j) * IE) * DV + d;  // e-stride DV
    WChunk c;
#pragma unroll
    for (int e = 0; e < IE; ++e) c.h[e] = (_Float16)src[(size_t)e * DV];
    Wc[t] = c.v;
}

__global__ void zero_kernel(float4* __restrict__ p) {
    p[blockIdx.x * blockDim.x + threadIdx.x] = make_float4(0.f, 0.f, 0.f, 0.f);
}

template <bool HASV>
__global__ __launch_bounds__(TPB, 5) void round_kernel(
    const float* __restrict__ X,     // [B, IC, IE] fp32
    const int4* __restrict__ Wc,     // coalesced fp16 layout (see wprep)
    const float* __restrict__ bias,  // [IC*NC] fp32
    const float* __restrict__ vws,   // v1 (round 1) or v1+v2 (round 2)
    float* __restrict__ s_ws)        // [B*160] accumulated via atomics
{
    __shared__ float lg[32 * 11];  // logits tile, padded stride 11
    __shared__ float rZ[32];       // per-row 1/sum(exp)

    const int Gp = blockIdx.x;   // 0..35
    const int bg = blockIdx.y;   // 0..31
    const int tid = threadIdx.x;
    const int j = tid >> 6;      // wave = output capsule
    const int g = tid & 63;
    const int h = g >> 5;        // d-half: d = h*8 + k
    const int r = g & 31;        // row within group
    const int i = Gp * 32 + r;

    // W fragment: 8 int4 (32 VGPRs), lane-consecutive => coalesced
    WChunk w[8];
    {
        const int4* wp = Wc + ((size_t)(Gp * NC + j) * 8) * 64 + g;
#pragma unroll
        for (int k = 0; k < 8; ++k) w[k].v = wp[k * 64];
    }
    const float lt_bias = bias[i * NC + j];

    float c0 = 0.f;
    if (!HASV) {
        // round 0: softmax(bias) is b-independent — compute once
        if (h == 0) lg[r * 11 + j] = lt_bias;
        __syncthreads();
        if (j == 0 && g < 32) {
            float Z = 0.f;
#pragma unroll
            for (int jj = 0; jj < NC; ++jj) Z += __expf(lg[g * 11 + jj]);
            rZ[g] = 1.f / Z;
        }
        __syncthreads();
        c0 = __expf(lt_bias) * rZ[r];
    }

    for (int bi = 0; bi < BT; ++bi) {
        const int b = bg * BT + bi;

        const float4* xr = (const float4*)(X + ((size_t)b * IC + i) * IE);
        float4 x0 = xr[0], x1 = xr[1];
        h2 x2[4];
        x2[0] = h2{(_Float16)x0.x, (_Float16)x0.y};
        x2[1] = h2{(_Float16)x0.z, (_Float16)x0.w};
        x2[2] = h2{(_Float16)x1.x, (_Float16)x1.y};
        x2[3] = h2{(_Float16)x1.z, (_Float16)x1.w};

        // hat[k] = hat[i,j, h*8+k] = sum_e x[e]*W[i,j,e,h*8+k]
        float hat[8];
#pragma unroll
        for (int k = 0; k < 8; ++k) {
            float a = 0.f;
#pragma unroll
            for (int q = 0; q < 4; ++q) a = fdot2(x2[q], w[k].p[q], a);
            hat[k] = a;
        }

        float c;
        if (HASV) {
            // agreement: half-dot + cross-half shuffle
            const float4* vp = (const float4*)(vws + (size_t)b * SOUT + j * DV + h * 8);
            float4 va = vp[0], vb = vp[1];
            const float vv[8] = {va.x, va.y, va.z, va.w, vb.x, vb.y, vb.z, vb.w};
            float ah = 0.f;
#pragma unroll
            for (int k = 0; k < 8; ++k) ah = fmaf(hat[k], vv[k], ah);
            const float lt = lt_bias + ah + __shfl_xor(ah, 32);

            if (h == 0) lg[r * 11 + j] = lt;
            __syncthreads();
            if (j == 0 && g < 32) {
                float Z = 0.f;
#pragma unroll
                for (int jj = 0; jj < NC; ++jj) Z += __expf(lg[g * 11 + jj]);
                rZ[g] = 1.f / Z;
            }
            __syncthreads();
            c = __expf(lt) * rZ[r];
        } else {
            c = c0;
        }

        float s8[8];
#pragma unroll
        for (int k = 0; k < 8; ++k) s8[k] = c * hat[k];

        // splitting butterfly over the 32 r-lanes of this d-half: 8->4->2->1
        float t4[4];
#pragma unroll
        for (int d = 0; d < 4; ++d) {
            bool hi = (r & 16);
            float mine = hi ? s8[d + 4] : s8[d];
            float send = hi ? s8[d] : s8[d + 4];
            t4[d] = mine + __shfl_xor(send, 16);
        }
        float t2[2];
#pragma unroll
        for (int d = 0; d < 2; ++d) {
            bool hi = (r & 8);
            float mine = hi ? t4[d + 2] : t4[d];
            float send = hi ? t4[d] : t4[d + 2];
            t2[d] = mine + __shfl_xor(send, 8);
        }
        float t1;
        {
            bool hi = (r & 4);
            float mine = hi ? t2[1] : t2[0];
            float send = hi ? t2[0] : t2[1];
            t1 = mine + __shfl_xor(send, 4);
        }
        t1 += __shfl_xor(t1, 2);
        t1 += __shfl_xor(t1, 1);

        if ((r & 3) == 0) {
            const int dl = (r >> 2) & 7;  // bit map: r4->d2, r3->d1, r2->d0
            atomicAdd(&s_ws[(size_t)b * SOUT + j * DV + h * 8 + dl], t1);
        }
    }
}

// vout = squash(s) (+ vprev if given)
__global__ __launch_bounds__(192) void squash_kernel(const float* __restrict__ s_ws,
                                                     const float* __restrict__ vprev,
                                                     float* __restrict__ vout) {
    const int b = blockIdx.x, t = threadIdx.x;
    if (t < SOUT) {
        float sv = s_ws[(size_t)b * SOUT + t];
        float s2 = sv * sv;
#pragma unroll
        for (int mk = 8; mk >= 1; mk >>= 1) s2 += __shfl_xor(s2, mk, 16);
        float scale = sqrtf(s2) / (1.f + s2);
        float vv = scale * sv;
        if (vprev) vv += vprev[(size_t)b * SOUT + t];
        vout[(size_t)b * SOUT + t] = vv;
    }
}

extern "C" void kernel_launch(void* const* d_in, const int* in_sizes, int n_in,
                              void* d_out, int out_size, void* d_ws, size_t ws_size,
                              hipStream_t stream) {
    const float* X = (const float*)d_in[0];     // [256,1152,8]
    const float* W = (const float*)d_in[1];     // [1152,10,8,16]
    const float* bias = (const float*)d_in[2];  // [1,1152,10]
    float* out = (float*)d_out;

    // ws (floats): Wc (NW/2) | s0 | s1 | s2 | v1 | vsum   = 3.77 MB
    float* base = (float*)d_ws;
    int4* Wc = (int4*)d_ws;
    float* s0 = base + NW / 2;
    float* s1 = s0 + SB;
    float* s2 = s1 + SB;
    float* v1 = s2 + SB;
    float* vsum = v1 + SB;

    wprep_kernel<<<dim3(720), dim3(256), 0, stream>>>(W, Wc);
    zero_kernel<<<dim3(120), dim3(256), 0, stream>>>((float4*)s0);  // s0,s1,s2

    dim3 rg(NGP, NBG);  // (36, 32)
    round_kernel<false><<<rg, TPB, 0, stream>>>(X, Wc, bias, nullptr, s0);
    squash_kernel<<<NB, 192, 0, stream>>>(s0, nullptr, v1);
    round_kernel<true><<<rg, TPB, 0, stream>>>(X, Wc, bias, v1, s1);
    squash_kernel<<<NB, 192, 0, stream>>>(s1, v1, vsum);  // vsum = v2 + v1
    round_kernel<true><<<rg, TPB, 0, stream>>>(X, Wc, bias, vsum, s2);
    squash_kernel<<<NB, 192, 0, stream>>>(s2, nullptr, out);
}